// Round 4
// baseline (450.036 us; speedup 1.0000x reference)
//
#include <hip/hip_runtime.h>
#include <hip/hip_cooperative_groups.h>

namespace cg = cooperative_groups;

#define EPSF 1e-8f
#define DD 128   // feature dim, fixed by problem

// ---------- small helpers ----------
__device__ __forceinline__ float4 ld4(const float* p){ return *reinterpret_cast<const float4*>(p); }
__device__ __forceinline__ void st4(float* p, const float4& v){ *reinterpret_cast<float4*>(p) = v; }
__device__ __forceinline__ float dot4(const float4& a, const float4& b){
  return a.x*b.x + a.y*b.y + a.z*b.z + a.w*b.w;
}
__device__ __forceinline__ void fma4(float4& acc, const float4& a, float s){
  acc.x += a.x*s; acc.y += a.y*s; acc.z += a.z*s; acc.w += a.w*s;
}
// (1-a)*v + a*x  (matches reference arithmetic order)
__device__ __forceinline__ float4 mix4(float a, const float4& v, const float4& x){
  float4 r;
  r.x = (1.f-a)*v.x + a*x.x;
  r.y = (1.f-a)*v.y + a*x.y;
  r.z = (1.f-a)*v.z + a*x.z;
  r.w = (1.f-a)*v.w + a*x.w;
  return r;
}
// butterfly sum over a 16-lane group (xor masks stay within the group)
__device__ __forceinline__ float red16(float v){
  v += __shfl_xor(v, 1);
  v += __shfl_xor(v, 2);
  v += __shfl_xor(v, 4);
  v += __shfl_xor(v, 8);
  return v;
}
// block-level reduction of 16 row-groups' (2x float4 per lane) partials into dst[0..127]
__device__ __forceinline__ void block_red16(float* red, int g, int l, int t,
                                            const float4& accA, const float4& accB,
                                            float* dst){
  red[g*DD + l*4+0] = accA.x;
  red[g*DD + l*4+1] = accA.y;
  red[g*DD + l*4+2] = accA.z;
  red[g*DD + l*4+3] = accA.w;
  red[g*DD + 64 + l*4+0] = accB.x;
  red[g*DD + 64 + l*4+1] = accB.y;
  red[g*DD + 64 + l*4+2] = accB.z;
  red[g*DD + 64 + l*4+3] = accB.w;
  __syncthreads();
  if (t < DD){
    float s = 0.f;
    #pragma unroll
    for (int q = 0; q < 16; ++q) s += red[q*DD + t];
    dst[t] = s;
  }
  __syncthreads();
}

// ---------- fused cooperative kernel: 7 phases with grid-wide syncs ----------
// onlyPhase = -1: run all phases with grid.sync() between (cooperative launch).
// onlyPhase = p : run just phase p, no grid sync (fallback multi-launch path).
__global__ __launch_bounds__(256, 4) void kFused(
    const float* __restrict__ at,   const float* __restrict__ addr,
    const float* __restrict__ tags, const float* __restrict__ col1,
    const float* __restrict__ col2, const float* __restrict__ zv,
    const int* __restrict__ gcp,
    float* __restrict__ o_t, float* __restrict__ o_1, float* __restrict__ o_2,
    float* __restrict__ w, int B, int N, int CH, int onlyPhase)
{
  cg::grid_group grid = cg::this_grid();
  __shared__ float red[16*DD];

  const size_t S  = (size_t)B * N;
  const size_t BD = (size_t)B * DD;
  float* cs0    = w;
  float* csfn   = w + S;
  float* alphap = w + 2*S;
  float* csbody = w + 3*S;
  float* s1f    = w + 4*S;
  float* s2f    = w + 5*S;
  float* naf    = w + 6*S;
  float* vecs   = w + 7*S;            // [10][B][D]: fn,arg,param,body,a_tag,a_l,a_r,b_tag,b_l,b_r
  float* part   = vecs + 10*BD;       // [<=5][B][CH][D], reused across stages

  const int blk = blockIdx.x;
  const int b = blk / CH, c = blk % CH;
  const int rows = N / CH, n0 = c * rows;
  const int t = threadIdx.x, g = t >> 4, l = t & 15;
  const size_t bN = (size_t)b * N;
  const int G = gridDim.x;

  // ---- P0: cs0, row norms; partials for fn, arg ----
  if (onlyPhase < 0 || onlyPhase == 0){
    const float* atp = at + (size_t)b*DD;
    float4 atA = ld4(atp + l*4), atB = ld4(atp + 64 + l*4);
    float nat = sqrtf(red16(dot4(atA, atA) + dot4(atB, atB)));
    float4 accFA = make_float4(0,0,0,0), accFB = accFA, accAA = accFA, accAB = accFA;
    #pragma unroll 2
    for (int r = g; r < rows; r += 16){
      size_t n = (size_t)n0 + r;
      size_t base = (bN + n)*DD;
      float4 aA  = ld4(addr + base + l*4), aB  = ld4(addr + base + 64 + l*4);
      float4 c1A = ld4(col1 + base + l*4), c1B = ld4(col1 + base + 64 + l*4);
      float4 c2A = ld4(col2 + base + l*4), c2B = ld4(col2 + base + 64 + l*4);
      float dp = red16(dot4(atA, aA) + dot4(atB, aB));
      float n2 = red16(dot4(aA, aA) + dot4(aB, aB));
      float na = sqrtf(n2);
      float cs = dp / fmaxf(nat * na, EPSF);
      if (l == 0){ cs0[bN + n] = cs; naf[bN + n] = na; }
      fma4(accFA, c1A, cs); fma4(accFB, c1B, cs);
      fma4(accAA, c2A, cs); fma4(accAB, c2B, cs);
    }
    block_red16(red, g, l, t, accFA, accFB, part + ((size_t)(0*B + b)*CH + c)*DD);
    block_red16(red, g, l, t, accAA, accAB, part + ((size_t)(1*B + b)*CH + c)*DD);
  }
  if (onlyPhase < 0) grid.sync();

  // ---- P1: reduce 2 vecs -> vecs[0..1] ----
  if (onlyPhase < 0 || onlyPhase == 1){
    int tot = 2*B*DD;
    for (int i = blk*256 + t; i < tot; i += G*256){
      int vb = i >> 7, d = i & (DD-1);
      const float* p = part + ((size_t)vb*CH)*DD + d;
      float s = 0.f;
      for (int cc = 0; cc < CH; ++cc) s += p[(size_t)cc*DD];
      vecs[i] = s;
    }
  }
  if (onlyPhase < 0) grid.sync();

  // ---- P2: csfn field; partials for param,body,a_tag,a_l,a_r ----
  if (onlyPhase < 0 || onlyPhase == 2){
    const float* fnp = vecs + (size_t)b*DD;
    const float* agp = vecs + BD + (size_t)b*DD;
    float4 fnA = ld4(fnp + l*4), fnB = ld4(fnp + 64 + l*4);
    float4 agA = ld4(agp + l*4), agB = ld4(agp + 64 + l*4);
    float nfn = sqrtf(red16(dot4(fnA, fnA) + dot4(fnB, fnB)));
    float nag = sqrtf(red16(dot4(agA, agA) + dot4(agB, agB)));
    float4 z = make_float4(0,0,0,0);
    float4 accPA=z, accPB=z, accBA=z, accBB=z, accTA=z, accTB=z, accLA=z, accLB=z, accRA=z, accRB=z;
    #pragma unroll 2
    for (int r = g; r < rows; r += 16){
      size_t n = (size_t)n0 + r;
      size_t base = (bN + n)*DD;
      float4 aA  = ld4(addr + base + l*4), aB  = ld4(addr + base + 64 + l*4);
      float4 t4A = ld4(tags + base + l*4), t4B = ld4(tags + base + 64 + l*4);
      float4 c1A = ld4(col1 + base + l*4), c1B = ld4(col1 + base + 64 + l*4);
      float4 c2A = ld4(col2 + base + l*4), c2B = ld4(col2 + base + 64 + l*4);
      float na = naf[bN + n];
      float dfn = red16(dot4(fnA, aA) + dot4(fnB, aB));
      float dag = red16(dot4(agA, aA) + dot4(agB, aB));
      float cf = dfn / fmaxf(nfn*na, EPSF);
      float ca = dag / fmaxf(nag*na, EPSF);
      if (l == 0) csfn[bN + n] = cf;
      fma4(accPA, c1A, cf); fma4(accPB, c1B, cf);
      fma4(accBA, c2A, cf); fma4(accBB, c2B, cf);
      fma4(accTA, t4A, ca); fma4(accTB, t4B, ca);
      fma4(accLA, c1A, ca); fma4(accLB, c1B, ca);
      fma4(accRA, c2A, ca); fma4(accRB, c2B, ca);
    }
    block_red16(red, g, l, t, accPA, accPB, part + ((size_t)(0*B + b)*CH + c)*DD);
    block_red16(red, g, l, t, accBA, accBB, part + ((size_t)(1*B + b)*CH + c)*DD);
    block_red16(red, g, l, t, accTA, accTB, part + ((size_t)(2*B + b)*CH + c)*DD);
    block_red16(red, g, l, t, accLA, accLB, part + ((size_t)(3*B + b)*CH + c)*DD);
    block_red16(red, g, l, t, accRA, accRB, part + ((size_t)(4*B + b)*CH + c)*DD);
  }
  if (onlyPhase < 0) grid.sync();

  // ---- P3: reduce 5 vecs -> vecs[2..6] ----
  if (onlyPhase < 0 || onlyPhase == 3){
    int tot = 5*B*DD;
    for (int i = blk*256 + t; i < tot; i += G*256){
      int vb = i >> 7, d = i & (DD-1);
      const float* p = part + ((size_t)vb*CH)*DD + d;
      float s = 0.f;
      for (int cc = 0; cc < CH; ++cc) s += p[(size_t)cc*DD];
      vecs[2*BD + i] = s;
    }
  }
  if (onlyPhase < 0) grid.sync();

  // ---- P4: row scalars ap,csb,s1,s2; partials for b_tag,b_l,b_r over updated rows ----
  if (onlyPhase < 0 || onlyPhase == 4){
    const float* vp = vecs + (size_t)b*DD;
    float4 agA = ld4(vp + 1*BD + l*4), agB = ld4(vp + 1*BD + 64 + l*4);
    float4 pmA = ld4(vp + 2*BD + l*4), pmB = ld4(vp + 2*BD + 64 + l*4);
    float4 bdA = ld4(vp + 3*BD + l*4), bdB = ld4(vp + 3*BD + 64 + l*4);
    float4 xtA = ld4(vp + 4*BD + l*4), xtB = ld4(vp + 4*BD + 64 + l*4);
    float4 xlA = ld4(vp + 5*BD + l*4), xlB = ld4(vp + 5*BD + 64 + l*4);
    float4 xrA = ld4(vp + 6*BD + l*4), xrB = ld4(vp + 6*BD + 64 + l*4);
    float npm = sqrtf(red16(dot4(pmA, pmA) + dot4(pmB, pmB)));
    float nbd = sqrtf(red16(dot4(bdA, bdA) + dot4(bdB, bdB)));
    float4 z = make_float4(0,0,0,0);
    float4 accTA=z, accTB=z, accLA=z, accLB=z, accRA=z, accRB=z;
    #pragma unroll 2
    for (int r = g; r < rows; r += 16){
      size_t n = (size_t)n0 + r;
      size_t base = (bN + n)*DD;
      float4 aA  = ld4(addr + base + l*4), aB  = ld4(addr + base + 64 + l*4);
      float4 t4A = ld4(tags + base + l*4), t4B = ld4(tags + base + 64 + l*4);
      float4 c1A = ld4(col1 + base + l*4), c1B = ld4(col1 + base + 64 + l*4);
      float4 c2A = ld4(col2 + base + l*4), c2B = ld4(col2 + base + 64 + l*4);
      float na = naf[bN + n];
      float dp = red16(dot4(pmA, aA) + dot4(pmB, aB));
      float db = red16(dot4(bdA, aA) + dot4(bdB, aB));
      float csp = dp / fmaxf(npm*na, EPSF);
      float ap  = csp > EPSF ? csp : 0.f;
      float csb = db / fmaxf(nbd*na, EPSF);

      float4 tnA  = mix4(ap, t4A, xtA), tnB  = mix4(ap, t4B, xtB);
      float4 c1nA = mix4(ap, c1A, xlA), c1nB = mix4(ap, c1B, xlB);
      float4 c2nA = mix4(ap, c2A, xrA), c2nB = mix4(ap, c2B, xrB);
      float d1  = red16(dot4(pmA, c1nA) + dot4(pmB, c1nB));
      float n21 = red16(dot4(c1nA, c1nA) + dot4(c1nB, c1nB));
      float s1 = d1 / fmaxf(npm * sqrtf(n21), EPSF);
      float4 c1fA = mix4(s1, c1nA, agA), c1fB = mix4(s1, c1nB, agB);
      float d2  = red16(dot4(pmA, c2nA) + dot4(pmB, c2nB));
      float n22 = red16(dot4(c2nA, c2nA) + dot4(c2nB, c2nB));
      float s2 = d2 / fmaxf(npm * sqrtf(n22), EPSF);
      float4 c2fA = mix4(s2, c2nA, agA), c2fB = mix4(s2, c2nB, agB);

      if (l == 0){
        alphap[bN + n] = ap;
        csbody[bN + n] = csb;
        s1f[bN + n] = s1;
        s2f[bN + n] = s2;
      }
      fma4(accTA, tnA,  csb); fma4(accTB, tnB,  csb);
      fma4(accLA, c1fA, csb); fma4(accLB, c1fB, csb);
      fma4(accRA, c2fA, csb); fma4(accRB, c2fB, csb);
    }
    block_red16(red, g, l, t, accTA, accTB, part + ((size_t)(0*B + b)*CH + c)*DD);
    block_red16(red, g, l, t, accLA, accLB, part + ((size_t)(1*B + b)*CH + c)*DD);
    block_red16(red, g, l, t, accRA, accRB, part + ((size_t)(2*B + b)*CH + c)*DD);
  }
  if (onlyPhase < 0) grid.sync();

  // ---- P5: reduce 3 vecs -> vecs[7..9] ----
  if (onlyPhase < 0 || onlyPhase == 5){
    int tot = 3*B*DD;
    for (int i = blk*256 + t; i < tot; i += G*256){
      int vb = i >> 7, d = i & (DD-1);
      const float* p = part + ((size_t)vb*CH)*DD + d;
      float s = 0.f;
      for (int cc = 0; cc < CH; ++cc) s += p[(size_t)cc*DD];
      vecs[7*BD + i] = s;
    }
  }
  if (onlyPhase < 0) grid.sync();

  // ---- P6: streaming final pass over this block's rows ----
  if (onlyPhase < 0 || onlyPhase == 6){
    const int l2 = t & 31;
    const int r0 = t >> 5;     // 8 row-slots of 32 lanes
    const float* vb = vecs + (size_t)b*DD + (size_t)l2*4;
    float4 ag = ld4(vb + 1*BD);
    float4 xt = ld4(vb + 4*BD), xl = ld4(vb + 5*BD), xr = ld4(vb + 6*BD);
    float4 bt = ld4(vb + 7*BD), bl = ld4(vb + 8*BD), br = ld4(vb + 9*BD);
    float4 z4 = ld4(zv + l2*4);
    int gcn = gcp[0];
    for (int r = r0; r < rows; r += 8){
      size_t bn = bN + (size_t)n0 + r;
      float ap = alphap[bn], s1 = s1f[bn], s2 = s2f[bn];
      float c0 = cs0[bn], cf = csfn[bn], cb = csbody[bn];
      float aat = c0 > EPSF ? c0 : 0.f;
      float af  = cf > EPSF ? cf : 0.f;
      float ab  = cb > EPSF ? cb : 0.f;
      float q = (1.f-af)*(1.f-ap)*(1.f-ab);
      float P = 1.f;
      for (int k = 0; k < gcn; ++k) P *= q;

      size_t off = bn*DD + (size_t)l2*4;
      float4 t4 = ld4(tags + off), c1 = ld4(col1 + off), c2 = ld4(col2 + off);
      float4 tn  = mix4(ap, t4, xt);                 // param insert
      float4 c1f = mix4(s1, mix4(ap, c1, xl), ag);   // + replace
      float4 c2f = mix4(s2, mix4(ap, c2, xr), ag);

      float4 u;
      u = mix4(aat, tn, bt);
      u.x = P*u.x + (1.f-P)*z4.x; u.y = P*u.y + (1.f-P)*z4.y;
      u.z = P*u.z + (1.f-P)*z4.z; u.w = P*u.w + (1.f-P)*z4.w;
      st4(o_t + off, u);
      u = mix4(aat, c1f, bl);
      u.x = P*u.x + (1.f-P)*z4.x; u.y = P*u.y + (1.f-P)*z4.y;
      u.z = P*u.z + (1.f-P)*z4.z; u.w = P*u.w + (1.f-P)*z4.w;
      st4(o_1 + off, u);
      u = mix4(aat, c2f, br);
      u.x = P*u.x + (1.f-P)*z4.x; u.y = P*u.y + (1.f-P)*z4.y;
      u.z = P*u.z + (1.f-P)*z4.z; u.w = P*u.w + (1.f-P)*z4.w;
      st4(o_2 + off, u);
    }
  }
}

extern "C" void kernel_launch(void* const* d_in, const int* in_sizes, int n_in,
                              void* d_out, int out_size, void* d_ws, size_t ws_size,
                              hipStream_t stream){
  const float* at   = (const float*)d_in[0];
  const float* addr = (const float*)d_in[1];
  const float* tags = (const float*)d_in[2];
  const float* col1 = (const float*)d_in[3];
  const float* col2 = (const float*)d_in[4];
  const float* zv   = (const float*)d_in[5];
  const int*   gc   = (const int*)d_in[6];

  int Dd = in_sizes[5];                 // 128
  int B  = in_sizes[0] / Dd;            // 32
  int N  = in_sizes[1] / in_sizes[0];   // 2048
  (void)Dd;

  size_t S  = (size_t)B * N;
  size_t BD = (size_t)B * DD;

  // co-residency capacity for cooperative launch
  int maxB = 0;
  if (hipOccupancyMaxActiveBlocksPerMultiprocessor(&maxB, kFused, 256, 0) != hipSuccess || maxB < 1)
    maxB = 1;
  long cap = (long)maxB * 256;          // 256 CUs on MI355X

  int CH = 32;
  while (CH > 1){
    bool fitw = (7*S + 10*BD + (size_t)5*B*CH*DD) * sizeof(float) <= ws_size;
    bool fitc = (long)B*CH <= cap;
    if (fitw && fitc && (N % CH) == 0) break;
    CH >>= 1;
  }
  int G = B * CH;

  float* w   = (float*)d_ws;
  float* o_t = (float*)d_out;
  float* o_1 = o_t + (size_t)B*N*DD;
  float* o_2 = o_1 + (size_t)B*N*DD;

  int onlyPhase = -1;
  void* args[] = {(void*)&at, (void*)&addr, (void*)&tags, (void*)&col1, (void*)&col2,
                  (void*)&zv, (void*)&gc, (void*)&o_t, (void*)&o_1, (void*)&o_2,
                  (void*)&w, (void*)&B, (void*)&N, (void*)&CH, (void*)&onlyPhase};
  hipError_t err = hipLaunchCooperativeKernel((const void*)kFused, dim3(G), dim3(256),
                                              args, 0, stream);
  if (err != hipSuccess){
    // fallback: same kernel, one launch per phase (kernel boundaries = sync)
    for (int p = 0; p < 7; ++p){
      hipLaunchKernelGGL(kFused, dim3(G), dim3(256), 0, stream,
                         at, addr, tags, col1, col2, zv, gc,
                         o_t, o_1, o_2, w, B, N, CH, p);
    }
  }
}

// Round 5
// 204.347 us; speedup vs baseline: 2.2023x; 2.2023x over previous
//
#include <hip/hip_runtime.h>

#define EPSF 1e-8f
#define DD 128   // feature dim, fixed by problem

// ---------- small helpers ----------
__device__ __forceinline__ float4 ld4(const float* p){ return *reinterpret_cast<const float4*>(p); }
__device__ __forceinline__ void st4(float* p, const float4& v){ *reinterpret_cast<float4*>(p) = v; }
__device__ __forceinline__ float dot4(const float4& a, const float4& b){
  return a.x*b.x + a.y*b.y + a.z*b.z + a.w*b.w;
}
__device__ __forceinline__ void fma4(float4& acc, const float4& a, float s){
  acc.x += a.x*s; acc.y += a.y*s; acc.z += a.z*s; acc.w += a.w*s;
}
// (1-a)*v + a*x  (matches reference arithmetic order)
__device__ __forceinline__ float4 mix4(float a, const float4& v, const float4& x){
  float4 r;
  r.x = (1.f-a)*v.x + a*x.x;
  r.y = (1.f-a)*v.y + a*x.y;
  r.z = (1.f-a)*v.z + a*x.z;
  r.w = (1.f-a)*v.w + a*x.w;
  return r;
}
// butterfly sum over a 16-lane group (xor masks stay within the group)
__device__ __forceinline__ float red16(float v){
  v += __shfl_xor(v, 1);
  v += __shfl_xor(v, 2);
  v += __shfl_xor(v, 4);
  v += __shfl_xor(v, 8);
  return v;
}
// block-level reduction of 16 row-groups' (2x float4 per lane) partials into dst[0..127]
__device__ __forceinline__ void block_red16(float* red, int g, int l, int t,
                                            const float4& accA, const float4& accB,
                                            float* dst){
  red[g*DD + l*4+0] = accA.x;
  red[g*DD + l*4+1] = accA.y;
  red[g*DD + l*4+2] = accA.z;
  red[g*DD + l*4+3] = accA.w;
  red[g*DD + 64 + l*4+0] = accB.x;
  red[g*DD + 64 + l*4+1] = accB.y;
  red[g*DD + 64 + l*4+2] = accB.z;
  red[g*DD + 64 + l*4+3] = accB.w;
  __syncthreads();
  if (t < DD){
    float s = 0.f;
    #pragma unroll
    for (int q = 0; q < 16; ++q) s += red[q*DD + t];
    dst[t] = s;
  }
  __syncthreads();
}

// per-block redundant reduction of nv per-batch partial vectors into LDS vsm[nv*DD].
// part layout: [(v*B + b)][CH][DD]; sequential-c sum order (bit-identical to old kFin).
__device__ __forceinline__ void reduce_vecs(const float* __restrict__ part, int B, int b,
                                            int CH, int nv, float* vsm, int t){
  for (int i = t; i < nv*DD; i += 256){
    int v = i >> 7, d = i & (DD-1);
    const float* p = part + ((size_t)(v*B + b)*CH)*DD + d;
    float s = 0.f;
    for (int c = 0; c < CH; ++c) s += p[(size_t)c*DD];
    vsm[i] = s;
  }
  __syncthreads();
}

// ---------- kernel A: cs0 + row norms; partials for fn,arg -> partA ----------
__global__ __launch_bounds__(256) void kA(const float* __restrict__ at,
                                          const float* __restrict__ addr,
                                          const float* __restrict__ col1,
                                          const float* __restrict__ col2,
                                          float* __restrict__ cs0,
                                          float* __restrict__ naf,
                                          float* __restrict__ partA,
                                          int B, int N, int CH){
  __shared__ float red[16*DD];
  int blk = blockIdx.x;
  int b = blk / CH, c = blk % CH;
  int rows = N / CH, n0 = c * rows;
  int t = threadIdx.x, g = t >> 4, l = t & 15;   // 16 groups of 16 lanes; group = 1 row
  size_t bN = (size_t)b * N;

  const float* atp = at + (size_t)b*DD;
  float4 atA = ld4(atp + l*4), atB = ld4(atp + 64 + l*4);
  float nat = sqrtf(red16(dot4(atA, atA) + dot4(atB, atB)));

  float4 accFA = make_float4(0,0,0,0), accFB = accFA, accAA = accFA, accAB = accFA;
  #pragma unroll 2
  for (int r = g; r < rows; r += 16){
    size_t n = (size_t)n0 + r;
    size_t base = (bN + n)*DD;
    float4 aA  = ld4(addr + base + l*4), aB  = ld4(addr + base + 64 + l*4);
    float4 c1A = ld4(col1 + base + l*4), c1B = ld4(col1 + base + 64 + l*4);
    float4 c2A = ld4(col2 + base + l*4), c2B = ld4(col2 + base + 64 + l*4);
    float dp = red16(dot4(atA, aA) + dot4(atB, aB));
    float n2 = red16(dot4(aA, aA) + dot4(aB, aB));
    float na = sqrtf(n2);
    float cs = dp / fmaxf(nat * na, EPSF);
    if (l == 0){ cs0[bN + n] = cs; naf[bN + n] = na; }
    fma4(accFA, c1A, cs); fma4(accFB, c1B, cs);
    fma4(accAA, c2A, cs); fma4(accAB, c2B, cs);
  }
  block_red16(red, g, l, t, accFA, accFB, partA + ((size_t)(0*B + b)*CH + c)*DD);
  block_red16(red, g, l, t, accAA, accAB, partA + ((size_t)(1*B + b)*CH + c)*DD);
}

// ---------- kernel B: reduce partA in-block; csfn field; partials -> partB ----------
__global__ __launch_bounds__(256) void kB(const float* __restrict__ addr,
                                          const float* __restrict__ tags,
                                          const float* __restrict__ col1,
                                          const float* __restrict__ col2,
                                          const float* __restrict__ partA,
                                          const float* __restrict__ naf,
                                          float* __restrict__ csfn,
                                          float* __restrict__ partB,
                                          int B, int N, int CH){
  __shared__ float red[16*DD];
  __shared__ float vsm[2*DD];            // fn, arg
  int blk = blockIdx.x;
  int b = blk / CH, c = blk % CH;
  int rows = N / CH, n0 = c * rows;
  int t = threadIdx.x, g = t >> 4, l = t & 15;
  size_t bN = (size_t)b * N;

  reduce_vecs(partA, B, b, CH, 2, vsm, t);

  float4 fnA = ld4(vsm + l*4),      fnB = ld4(vsm + 64 + l*4);
  float4 agA = ld4(vsm + DD + l*4), agB = ld4(vsm + DD + 64 + l*4);
  float nfn = sqrtf(red16(dot4(fnA, fnA) + dot4(fnB, fnB)));
  float nag = sqrtf(red16(dot4(agA, agA) + dot4(agB, agB)));

  float4 z = make_float4(0,0,0,0);
  float4 accPA=z, accPB=z, accBA=z, accBB=z, accTA=z, accTB=z, accLA=z, accLB=z, accRA=z, accRB=z;
  #pragma unroll 2
  for (int r = g; r < rows; r += 16){
    size_t n = (size_t)n0 + r;
    size_t base = (bN + n)*DD;
    float4 aA  = ld4(addr + base + l*4), aB  = ld4(addr + base + 64 + l*4);
    float4 t4A = ld4(tags + base + l*4), t4B = ld4(tags + base + 64 + l*4);
    float4 c1A = ld4(col1 + base + l*4), c1B = ld4(col1 + base + 64 + l*4);
    float4 c2A = ld4(col2 + base + l*4), c2B = ld4(col2 + base + 64 + l*4);
    float na = naf[bN + n];
    float dfn = red16(dot4(fnA, aA) + dot4(fnB, aB));
    float dag = red16(dot4(agA, aA) + dot4(agB, aB));
    float cf = dfn / fmaxf(nfn*na, EPSF);
    float ca = dag / fmaxf(nag*na, EPSF);
    if (l == 0) csfn[bN + n] = cf;
    fma4(accPA, c1A, cf); fma4(accPB, c1B, cf);      // param_addr
    fma4(accBA, c2A, cf); fma4(accBB, c2B, cf);      // body_addr
    fma4(accTA, t4A, ca); fma4(accTB, t4B, ca);      // a_tag
    fma4(accLA, c1A, ca); fma4(accLB, c1B, ca);      // a_l
    fma4(accRA, c2A, ca); fma4(accRB, c2B, ca);      // a_r
  }
  block_red16(red, g, l, t, accPA, accPB, partB + ((size_t)(0*B + b)*CH + c)*DD);
  block_red16(red, g, l, t, accBA, accBB, partB + ((size_t)(1*B + b)*CH + c)*DD);
  block_red16(red, g, l, t, accTA, accTB, partB + ((size_t)(2*B + b)*CH + c)*DD);
  block_red16(red, g, l, t, accLA, accLB, partB + ((size_t)(3*B + b)*CH + c)*DD);
  block_red16(red, g, l, t, accRA, accRB, partB + ((size_t)(4*B + b)*CH + c)*DD);
}

// ---------- kernel C: reduce partA(arg)+partB in-block; row scalars; partials -> partC ----------
__global__ __launch_bounds__(256) void kC(const float* __restrict__ addr,
                                          const float* __restrict__ tags,
                                          const float* __restrict__ col1,
                                          const float* __restrict__ col2,
                                          const float* __restrict__ partA,
                                          const float* __restrict__ partB,
                                          const float* __restrict__ naf,
                                          float* __restrict__ alphap,
                                          float* __restrict__ csbody,
                                          float* __restrict__ s1f,
                                          float* __restrict__ s2f,
                                          float* __restrict__ partC,
                                          int B, int N, int CH){
  __shared__ float red[16*DD];
  __shared__ float vsm[6*DD];            // [ag, param, body, a_tag, a_l, a_r]
  int blk = blockIdx.x;
  int b = blk / CH, c = blk % CH;
  int rows = N / CH, n0 = c * rows;
  int t = threadIdx.x, g = t >> 4, l = t & 15;
  size_t bN = (size_t)b * N;

  // ag from partA vec1; param..a_r from partB vec0..4
  reduce_vecs(partA + (size_t)(1*B)*CH*DD, B, b, CH, 1, vsm, t);
  reduce_vecs(partB, B, b, CH, 5, vsm + DD, t);

  float4 agA = ld4(vsm + 0*DD + l*4), agB = ld4(vsm + 0*DD + 64 + l*4);
  float4 pmA = ld4(vsm + 1*DD + l*4), pmB = ld4(vsm + 1*DD + 64 + l*4);
  float4 bdA = ld4(vsm + 2*DD + l*4), bdB = ld4(vsm + 2*DD + 64 + l*4);
  float4 xtA = ld4(vsm + 3*DD + l*4), xtB = ld4(vsm + 3*DD + 64 + l*4);
  float4 xlA = ld4(vsm + 4*DD + l*4), xlB = ld4(vsm + 4*DD + 64 + l*4);
  float4 xrA = ld4(vsm + 5*DD + l*4), xrB = ld4(vsm + 5*DD + 64 + l*4);
  float npm = sqrtf(red16(dot4(pmA, pmA) + dot4(pmB, pmB)));
  float nbd = sqrtf(red16(dot4(bdA, bdA) + dot4(bdB, bdB)));

  float4 z = make_float4(0,0,0,0);
  float4 accTA=z, accTB=z, accLA=z, accLB=z, accRA=z, accRB=z;
  #pragma unroll 2
  for (int r = g; r < rows; r += 16){
    size_t n = (size_t)n0 + r;
    size_t base = (bN + n)*DD;
    float4 aA  = ld4(addr + base + l*4), aB  = ld4(addr + base + 64 + l*4);
    float4 t4A = ld4(tags + base + l*4), t4B = ld4(tags + base + 64 + l*4);
    float4 c1A = ld4(col1 + base + l*4), c1B = ld4(col1 + base + 64 + l*4);
    float4 c2A = ld4(col2 + base + l*4), c2B = ld4(col2 + base + 64 + l*4);
    float na = naf[bN + n];
    float dp = red16(dot4(pmA, aA) + dot4(pmB, aB));
    float db = red16(dot4(bdA, aA) + dot4(bdB, aB));
    float csp = dp / fmaxf(npm*na, EPSF);
    float ap  = csp > EPSF ? csp : 0.f;
    float csb = db / fmaxf(nbd*na, EPSF);

    // kv_insert with param_addr
    float4 tnA  = mix4(ap, t4A, xtA), tnB  = mix4(ap, t4B, xtB);
    float4 c1nA = mix4(ap, c1A, xlA), c1nB = mix4(ap, c1B, xlB);
    float4 c2nA = mix4(ap, c2A, xrA), c2nB = mix4(ap, c2B, xrB);
    // replace(arg_addr, param_addr, ·): sim vs updated row itself (no clamp)
    float d1  = red16(dot4(pmA, c1nA) + dot4(pmB, c1nB));
    float n21 = red16(dot4(c1nA, c1nA) + dot4(c1nB, c1nB));
    float s1 = d1 / fmaxf(npm * sqrtf(n21), EPSF);
    float4 c1fA = mix4(s1, c1nA, agA), c1fB = mix4(s1, c1nB, agB);
    float d2  = red16(dot4(pmA, c2nA) + dot4(pmB, c2nB));
    float n22 = red16(dot4(c2nA, c2nA) + dot4(c2nB, c2nB));
    float s2 = d2 / fmaxf(npm * sqrtf(n22), EPSF);
    float4 c2fA = mix4(s2, c2nA, agA), c2fB = mix4(s2, c2nB, agB);

    if (l == 0){
      alphap[bN + n] = ap;
      csbody[bN + n] = csb;
      s1f[bN + n] = s1;
      s2f[bN + n] = s2;
    }
    // select_address(body_addr, ...) over UPDATED tensors
    fma4(accTA, tnA,  csb); fma4(accTB, tnB,  csb);
    fma4(accLA, c1fA, csb); fma4(accLB, c1fB, csb);
    fma4(accRA, c2fA, csb); fma4(accRB, c2fB, csb);
  }
  block_red16(red, g, l, t, accTA, accTB, partC + ((size_t)(0*B + b)*CH + c)*DD);
  block_red16(red, g, l, t, accLA, accLB, partC + ((size_t)(1*B + b)*CH + c)*DD);
  block_red16(red, g, l, t, accRA, accRB, partC + ((size_t)(2*B + b)*CH + c)*DD);
}

// ---------- kernel E: reduce needed vecs in-block; streaming final pass ----------
__global__ __launch_bounds__(256) void kE(const float* __restrict__ tags,
                                          const float* __restrict__ col1,
                                          const float* __restrict__ col2,
                                          float* __restrict__ o_t,
                                          float* __restrict__ o_1,
                                          float* __restrict__ o_2,
                                          const float* __restrict__ cs0,
                                          const float* __restrict__ csfn,
                                          const float* __restrict__ alphap,
                                          const float* __restrict__ csbody,
                                          const float* __restrict__ s1f,
                                          const float* __restrict__ s2f,
                                          const float* __restrict__ partA,
                                          const float* __restrict__ partB,
                                          const float* __restrict__ partC,
                                          const float* __restrict__ zv,
                                          const int* __restrict__ gcp,
                                          int B, int N, int CH){
  __shared__ float vsm[7*DD];            // [ag, xt, xl, xr, bt, bl, br]
  int blk = blockIdx.x;
  int b = blk / CH, c = blk % CH;
  int rows = N / CH, n0 = c * rows;
  int t = threadIdx.x;
  size_t bN = (size_t)b * N;

  reduce_vecs(partA + (size_t)(1*B)*CH*DD, B, b, CH, 1, vsm, t);          // ag
  reduce_vecs(partB + (size_t)(2*B)*CH*DD, B, b, CH, 3, vsm + DD, t);     // xt,xl,xr
  reduce_vecs(partC, B, b, CH, 3, vsm + 4*DD, t);                          // bt,bl,br

  const int l2 = t & 31;
  const int r0 = t >> 5;     // 8 row-slots of 32 lanes
  float4 ag = ld4(vsm + 0*DD + l2*4);
  float4 xt = ld4(vsm + 1*DD + l2*4), xl = ld4(vsm + 2*DD + l2*4), xr = ld4(vsm + 3*DD + l2*4);
  float4 bt = ld4(vsm + 4*DD + l2*4), bl = ld4(vsm + 5*DD + l2*4), br = ld4(vsm + 6*DD + l2*4);
  float4 z4 = ld4(zv + l2*4);
  int gcn = gcp[0];

  for (int r = r0; r < rows; r += 8){
    size_t bn = bN + (size_t)n0 + r;
    float ap = alphap[bn], s1 = s1f[bn], s2 = s2f[bn];
    float c0 = cs0[bn], cf = csfn[bn], cb = csbody[bn];
    float aat = c0 > EPSF ? c0 : 0.f;
    float af  = cf > EPSF ? cf : 0.f;
    float ab  = cb > EPSF ? cb : 0.f;
    float q = (1.f-af)*(1.f-ap)*(1.f-ab);
    float P = 1.f;
    for (int k = 0; k < gcn; ++k) P *= q;

    size_t off = bn*DD + (size_t)l2*4;
    float4 t4 = ld4(tags + off), c1 = ld4(col1 + off), c2 = ld4(col2 + off);
    float4 tn  = mix4(ap, t4, xt);                 // param insert
    float4 c1f = mix4(s1, mix4(ap, c1, xl), ag);   // + replace
    float4 c2f = mix4(s2, mix4(ap, c2, xr), ag);

    float4 u;
    u = mix4(aat, tn, bt);                         // body insert at App node
    u.x = P*u.x + (1.f-P)*z4.x; u.y = P*u.y + (1.f-P)*z4.y;
    u.z = P*u.z + (1.f-P)*z4.z; u.w = P*u.w + (1.f-P)*z4.w;
    st4(o_t + off, u);
    u = mix4(aat, c1f, bl);
    u.x = P*u.x + (1.f-P)*z4.x; u.y = P*u.y + (1.f-P)*z4.y;
    u.z = P*u.z + (1.f-P)*z4.z; u.w = P*u.w + (1.f-P)*z4.w;
    st4(o_1 + off, u);
    u = mix4(aat, c2f, br);
    u.x = P*u.x + (1.f-P)*z4.x; u.y = P*u.y + (1.f-P)*z4.y;
    u.z = P*u.z + (1.f-P)*z4.z; u.w = P*u.w + (1.f-P)*z4.w;
    st4(o_2 + off, u);
  }
}

extern "C" void kernel_launch(void* const* d_in, const int* in_sizes, int n_in,
                              void* d_out, int out_size, void* d_ws, size_t ws_size,
                              hipStream_t stream){
  const float* at   = (const float*)d_in[0];
  const float* addr = (const float*)d_in[1];
  const float* tags = (const float*)d_in[2];
  const float* col1 = (const float*)d_in[3];
  const float* col2 = (const float*)d_in[4];
  const float* zv   = (const float*)d_in[5];
  const int*   gc   = (const int*)d_in[6];

  int Dd = in_sizes[5];                 // 128
  int B  = in_sizes[0] / Dd;            // 32
  int N  = in_sizes[1] / in_sizes[0];   // 2048
  (void)Dd;

  size_t S  = (size_t)B * N;

  // chunks per batch: 32 -> grid 1024 blocks (4/CU); shrink if ws too small
  int CH = 32;
  while (CH > 1){
    size_t need = (7*S + (size_t)10*B*CH*DD) * sizeof(float);
    if (need <= ws_size && (N % CH) == 0) break;
    CH >>= 1;
  }

  // workspace layout (floats)
  float* w = (float*)d_ws;
  float* cs0    = w;
  float* csfn   = w + S;
  float* alphap = w + 2*S;
  float* csbody = w + 3*S;
  float* s1f    = w + 4*S;
  float* s2f    = w + 5*S;
  float* naf    = w + 6*S;
  float* partA  = w + 7*S;                               // [2][B][CH][DD]
  float* partB  = partA + (size_t)2*B*CH*DD;             // [5][B][CH][DD]
  float* partC  = partB + (size_t)5*B*CH*DD;             // [3][B][CH][DD]

  float* o_t = (float*)d_out;
  float* o_1 = o_t + (size_t)B*N*DD;
  float* o_2 = o_1 + (size_t)B*N*DD;

  dim3 blk(256);
  dim3 grid(B*CH);

  kA<<<grid, blk, 0, stream>>>(at, addr, col1, col2, cs0, naf, partA, B, N, CH);
  kB<<<grid, blk, 0, stream>>>(addr, tags, col1, col2, partA, naf, csfn, partB, B, N, CH);
  kC<<<grid, blk, 0, stream>>>(addr, tags, col1, col2, partA, partB, naf,
                               alphap, csbody, s1f, s2f, partC, B, N, CH);
  kE<<<grid, blk, 0, stream>>>(tags, col1, col2, o_t, o_1, o_2,
                               cs0, csfn, alphap, csbody, s1f, s2f,
                               partA, partB, partC, zv, gc, B, N, CH);
}